// Round 8
// baseline (162.869 us; speedup 1.0000x reference)
//
#include <hip/hip_runtime.h>
#include <hip/hip_bf16.h>

#define EPSV 1e-5f

typedef __attribute__((ext_vector_type(8))) short short8;
typedef __attribute__((ext_vector_type(4))) float f32x4;

__device__ __forceinline__ void gl_lds16(const void* g, void* l) {
    __builtin_amdgcn_global_load_lds(
        (const __attribute__((address_space(1))) unsigned int*)g,
        (__attribute__((address_space(3))) unsigned int*)l, 16, 0, 0);
}

__device__ __forceinline__ unsigned int bl2(unsigned int a, unsigned int b,
                                            unsigned int c, unsigned int d,
                                            float w00, float w01, float w10, float w11) {
    float lo = __uint_as_float(a << 16) * w00 + __uint_as_float(b << 16) * w01
             + __uint_as_float(c << 16) * w10 + __uint_as_float(d << 16) * w11;
    float hi = __uint_as_float(a & 0xffff0000u) * w00 + __uint_as_float(b & 0xffff0000u) * w01
             + __uint_as_float(c & 0xffff0000u) * w10 + __uint_as_float(d & 0xffff0000u) * w11;
    return ((unsigned int)__bfloat16_as_ushort(__float2bfloat16(lo)))
         | (((unsigned int)__bfloat16_as_ushort(__float2bfloat16(hi))) << 16);
}

__device__ __forceinline__ unsigned int pk2(float a, float b) {
    return ((unsigned int)__bfloat16_as_ushort(__float2bfloat16(a)))
         | (((unsigned int)__bfloat16_as_ushort(__float2bfloat16(b))) << 16);
}

// ---------- k_pre: transpose (bf16 hi+lo NHWC) + pack conv_w + pack offset_w hi/lo + zero stats ----------
__global__ __launch_bounds__(256) void k_pre(const float* __restrict__ f,
                                             const float* __restrict__ cw,
                                             const float* __restrict__ ow,
                                             ushort* __restrict__ fbh,
                                             ushort* __restrict__ flo,
                                             ushort* __restrict__ wpk,
                                             ushort* __restrict__ wpk2,
                                             float* __restrict__ stats) {
    int blk = blockIdx.x;
    int t = threadIdx.x;
    if (blk < 1024) {
        __shared__ float tile[64][65];
        int xt = blk & 1;
        int y  = (blk >> 1) & 127;
        int b  = blk >> 8;
        int x = t & 63, c0 = t >> 6;
        const float* src = f + (((size_t)b * 64) * 128 + y) * 128 + xt * 64;
#pragma unroll
        for (int i = 0; i < 64; i += 4)
            tile[c0 + i][x] = src[(size_t)(c0 + i) * 16384 + x];
        __syncthreads();
        size_t dbase = (((size_t)b * 128 + y) * 128 + xt * 64) * 64;
        int cc = t & 63, x0 = t >> 6;
#pragma unroll
        for (int i = 0; i < 64; i += 4) {
            float v = tile[cc][x0 + i];
            ushort hi = __bfloat16_as_ushort(__float2bfloat16(v));
            float vhi = __uint_as_float((unsigned int)hi << 16);
            ushort lo = __bfloat16_as_ushort(__float2bfloat16(v - vhi));
            fbh[dbase + (size_t)(x0 + i) * 64 + cc] = hi;
            flo[dbase + (size_t)(x0 + i) * 64 + cc] = lo;
        }
    } else if (blk < 1168) {
        int idx = (blk - 1024) * 256 + t;   // 36864
        int j  = idx & 7;
        int l  = (idx >> 3) & 63;
        int ot = (idx >> 9) & 3;
        int kk = (idx >> 11) & 1;
        int k  = idx >> 12;
        int c  = kk * 32 + ((l >> 4) << 3) + j;
        int oc = (ot << 4) + (l & 15);
        wpk[idx] = __bfloat16_as_ushort(__float2bfloat16(cw[((size_t)oc * 64 + c) * 9 + k]));
        if (idx < 128) stats[idx] = 0.f;
    } else {
        int idx = (blk - 1168) * 256 + t;   // 9216
        int j   = idx & 7;
        int l   = (idx >> 3) & 63;
        int kk  = (idx >> 9) & 1;
        int tap = idx >> 10;
        int c   = kk * 32 + ((l >> 4) << 3) + j;
        int n   = l & 15;
        float v = (n < 9) ? ow[((size_t)n * 64 + c) * 9 + tap] : 0.f;
        ushort hi = __bfloat16_as_ushort(__float2bfloat16(v));
        float vhi = __uint_as_float((unsigned int)hi << 16);
        ushort lo = __bfloat16_as_ushort(__float2bfloat16(v - vhi));
        wpk2[idx] = hi;
        wpk2[idx + 9216] = lo;
    }
}

// ---------- k_fused: LDS-window staged; offset conv (split-bf16 MFMA) + sample + main MFMA + GN stats ----------
__global__ __launch_bounds__(256, 3) void k_fused(
    const ushort* __restrict__ fbh,
    const ushort* __restrict__ flo,
    const ushort* __restrict__ wpk,
    const ushort* __restrict__ wpk2,
    const float* __restrict__ ob, const float* __restrict__ bng,
    const float* __restrict__ bnb, const float* __restrict__ bnm,
    const float* __restrict__ bnv, const float* __restrict__ cb,
    ushort* __restrict__ z, float* __restrict__ stats)
{
    // window: 9 rows (phys order {w-1,w,w+1,w-4,w-3,w-2,w+2,w+3,w+4}) x 42 cols x 64ch bf16
    // per (row,col): 8 chunks of 16B, chunk d holds source chunk d^(col&7)  [T21 swizzle]
    __shared__ union {
        struct {
            ushort win[24192];        // 48384 B
            float  tup[9][32][4];     // wy0, wy1, rowbyte0, rowbyte1 (4608 B; cs overlaid)
        } p;
        float Z2[32 * 65];            // epilogue transpose overlay
    } sm;
    __shared__ float redS[16], redQ[16];

    int jb = blockIdx.x;                 // grid 2048, chunked XCD swizzle
    int orig = (jb & 7) * 256 + (jb >> 3);
    int hq = orig & 3;
    int w  = (orig >> 2) & 127;
    int b  = orig >> 9;
    int h0 = hq << 5;
    int t    = threadIdx.x;
    int lane = t & 63;
    int wid  = t >> 6;
    int m = wid & 1;
    int n = wid >> 1;
    const char* winb = (const char*)sm.p.win;

    // ---- stage window: 11 full passes + guarded tail (48384 B exactly); rows w-1..w+1 first ----
#pragma unroll
    for (int p = 0; p < 12; ++p) {
        if (p == 11 && t >= 208) break;        // 11*4096 + 208*16 = 48384
        int ib = p * 4096 + t * 16;
        int ri = ib / 5376;
        int wb = ib - ri * 5376;
        int dys = ri < 3 ? ri + 3 : (ri < 6 ? ri - 3 : ri);   // phys -> dyslot
        int grow = min(max(w + dys - 4, 0), 127);
        int colIdx = wb >> 7;
        int c16 = (wb >> 4) & 7;
        int gcol = min(max(h0 - 5 + colIdx, 0), 127);
        int sch = c16 ^ (colIdx & 7);
        const ushort* src = fbh + ((((size_t)b << 7) + grow) * 128 + gcol) * 64 + (sch << 3);
        gl_lds16(src, (void*)(winb + ib));
    }
    asm volatile("s_waitcnt vmcnt(8)" ::: "memory");   // passes 0-3 landed -> rows w-1..w+1 complete
    __builtin_amdgcn_sched_barrier(0);
    __syncthreads();

    // ---- phase 0: offset conv, waves 0-1, hi from window + lo from global, split-bf16 ----
    if (wid < 2) {
        f32x4 acck = {0.f, 0.f, 0.f, 0.f};
        const short8* wp2 = (const short8*)wpk2;
        int px0 = (m << 4) + (lane & 15);
        int q = lane >> 4;
#pragma unroll
        for (int tap = 0; tap < 9; ++tap) {
            int dy = tap / 3, dx = tap - dy * 3;
            int ysrc = w + dy - 1;
            if ((unsigned)ysrc < 128u) {               // wave-uniform zero-pad skip
                int col = h0 + px0 + dx - 1;
                bool ok = (unsigned)col < 128u;
                int xslot = px0 + dx + 4;
                int rbase = dy * 5376 + (xslot << 7);  // rows w-1..w+1 are phys 0..2
                uint4 h0v = *(const uint4*)(winb + rbase + ((q ^ (xslot & 7)) << 4));
                uint4 h1v = *(const uint4*)(winb + rbase + (((q + 4) ^ (xslot & 7)) << 4));
                int colc = min(max(col, 0), 127);
                const ushort* lsrc = flo + ((((size_t)b << 7) + ysrc) * 128 + colc) * 64 + (q << 3);
                uint4 l0v = *(const uint4*)lsrc;
                uint4 l1v = *(const uint4*)(lsrc + 32);
                if (!ok) {
                    h0v = make_uint4(0, 0, 0, 0); h1v = make_uint4(0, 0, 0, 0);
                    l0v = make_uint4(0, 0, 0, 0); l1v = make_uint4(0, 0, 0, 0);
                }
                short8 wh0 = wp2[(tap * 2 + 0) * 64 + lane];
                short8 wh1 = wp2[(tap * 2 + 1) * 64 + lane];
                short8 wl0 = wp2[1152 + (tap * 2 + 0) * 64 + lane];
                short8 wl1 = wp2[1152 + (tap * 2 + 1) * 64 + lane];
                short8 ah0 = *(short8*)&h0v, ah1 = *(short8*)&h1v;
                short8 al0 = *(short8*)&l0v, al1 = *(short8*)&l1v;
                acck = __builtin_amdgcn_mfma_f32_16x16x32_bf16(ah0, wh0, acck, 0, 0, 0);
                acck = __builtin_amdgcn_mfma_f32_16x16x32_bf16(al0, wh0, acck, 0, 0, 0);
                acck = __builtin_amdgcn_mfma_f32_16x16x32_bf16(ah0, wl0, acck, 0, 0, 0);
                acck = __builtin_amdgcn_mfma_f32_16x16x32_bf16(ah1, wh1, acck, 0, 0, 0);
                acck = __builtin_amdgcn_mfma_f32_16x16x32_bf16(al1, wh1, acck, 0, 0, 0);
                acck = __builtin_amdgcn_mfma_f32_16x16x32_bf16(ah1, wl1, acck, 0, 0, 0);
            }
        }
        float* csm = (float*)sm.p.tup;   // cs overlay (288 floats)
#pragma unroll
        for (int r = 0; r < 4; ++r) {
            int pxo = (m << 4) + ((lane >> 4) << 2) + r;
            int ko = lane & 15;
            if (ko < 9) csm[pxo * 9 + ko] = acck[r];
        }
    }
    asm volatile("s_waitcnt vmcnt(0)" ::: "memory");   // rest of window landed
    __syncthreads();

    // ---- finalize: BN + tanh + cumsum + y-geometry -> tup (wave 0, lanes 0-31) ----
    if (t < 32) {
        const float* csm = (const float*)sm.p.tup;
        float tk[9];
#pragma unroll
        for (int k = 0; k < 9; ++k) {
            float zz = csm[t * 9 + k] + ob[k];
            zz = (zz - bnm[k]) * rsqrtf(bnv[k] + EPSV);
            zz = zz * bng[k] + bnb[k];
            tk[k] = tanhf(zz);
        }
        float nw_[9];
        nw_[4] = 0.f;
        nw_[5] = tk[5];
        nw_[6] = nw_[5] + tk[6];
        nw_[7] = nw_[6] + tk[7];
        nw_[8] = tk[8];
        nw_[3] = tk[3];
        nw_[2] = nw_[3] + tk[2];
        nw_[1] = nw_[2] + tk[1];
        nw_[0] = tk[0];
#pragma unroll
        for (int k = 0; k < 9; ++k) {
            float ys = (float)w + nw_[k];
            int y0 = min(max((int)floorf(ys), 0), 127);
            int y1 = min(y0 + 1, 127);
            float wy0 = (float)y1 - ys, wy1 = ys - (float)y0;
            int d0 = min(max(y0 - w + 4, 0), 8);
            int d1 = min(max(y1 - w + 4, 0), 8);
            int p0 = d0 < 3 ? d0 + 3 : (d0 < 6 ? d0 - 3 : d0);
            int p1 = d1 < 3 ? d1 + 3 : (d1 < 6 ? d1 - 3 : d1);
            float4 tv;
            tv.x = wy0; tv.y = wy1;
            tv.z = __int_as_float(p0 * 5376);
            tv.w = __int_as_float(p1 * 5376);
            *(float4*)sm.p.tup[k][t] = tv;
        }
    }
    __syncthreads();

    // ---- phase 1: per-lane bilerp fragments from window + main MFMA (no barriers) ----
    f32x4 acc0 = {0.f, 0.f, 0.f, 0.f};
    f32x4 acc1 = {0.f, 0.f, 0.f, 0.f};
    const short8* wp8 = (const short8*)wpk;
    int px = (lane & 15) + (m << 4);
    int q  = lane >> 4;
    float fpx = (float)(h0 + px);
#pragma unroll 3
    for (int k = 0; k < 9; ++k) {
        float4 tv = *(const float4*)sm.p.tup[k][px];
        float xs = fpx + (-5.0f + 1.125f * (float)k);
        int x0 = min(max((int)floorf(xs), 0), 127);
        int x1 = min(x0 + 1, 127);
        float wx0 = (float)x1 - xs;
        float wx1 = xs - (float)x0;
        float w00 = tv.x * wx0, w01 = tv.x * wx1, w10 = tv.y * wx0, w11 = tv.y * wx1;
        int rb0 = __float_as_int(tv.z), rb1 = __float_as_int(tv.w);
        int cx0 = x0 - h0 + 5, cx1 = x1 - h0 + 5;
        int s00 = rb0 + (cx0 << 7), s01 = rb0 + (cx1 << 7);
        int s10 = rb1 + (cx0 << 7), s11 = rb1 + (cx1 << 7);
        int qa0 = (q ^ (cx0 & 7)) << 4,       qa1 = (q ^ (cx1 & 7)) << 4;
        int qb0 = ((q + 4) ^ (cx0 & 7)) << 4, qb1 = ((q + 4) ^ (cx1 & 7)) << 4;
        uint4 a00 = *(const uint4*)(winb + s00 + qa0);
        uint4 a01 = *(const uint4*)(winb + s01 + qa1);
        uint4 a10 = *(const uint4*)(winb + s10 + qa0);
        uint4 a11 = *(const uint4*)(winb + s11 + qa1);
        uint4 b00 = *(const uint4*)(winb + s00 + qb0);
        uint4 b01 = *(const uint4*)(winb + s01 + qb1);
        uint4 b10 = *(const uint4*)(winb + s10 + qb0);
        uint4 b11 = *(const uint4*)(winb + s11 + qb1);
        uint4 f0u, f1u;
        f0u.x = bl2(a00.x, a01.x, a10.x, a11.x, w00, w01, w10, w11);
        f0u.y = bl2(a00.y, a01.y, a10.y, a11.y, w00, w01, w10, w11);
        f0u.z = bl2(a00.z, a01.z, a10.z, a11.z, w00, w01, w10, w11);
        f0u.w = bl2(a00.w, a01.w, a10.w, a11.w, w00, w01, w10, w11);
        f1u.x = bl2(b00.x, b01.x, b10.x, b11.x, w00, w01, w10, w11);
        f1u.y = bl2(b00.y, b01.y, b10.y, b11.y, w00, w01, w10, w11);
        f1u.z = bl2(b00.z, b01.z, b10.z, b11.z, w00, w01, w10, w11);
        f1u.w = bl2(b00.w, b01.w, b10.w, b11.w, w00, w01, w10, w11);
        short8 af0 = *(short8*)&f0u, af1 = *(short8*)&f1u;
        int fb0 = (k * 8 + (n << 1)) * 64 + lane;
        short8 wf00 = wp8[fb0];
        short8 wf01 = wp8[fb0 + 64];
        short8 wf10 = wp8[fb0 + 256];
        short8 wf11 = wp8[fb0 + 320];
        acc0 = __builtin_amdgcn_mfma_f32_16x16x32_bf16(af0, wf00, acc0, 0, 0, 0);
        acc0 = __builtin_amdgcn_mfma_f32_16x16x32_bf16(af1, wf10, acc0, 0, 0, 0);
        acc1 = __builtin_amdgcn_mfma_f32_16x16x32_bf16(af0, wf01, acc1, 0, 0, 0);
        acc1 = __builtin_amdgcn_mfma_f32_16x16x32_bf16(af1, wf11, acc1, 0, 0, 0);
    }

    // ---- epilogue: bias, GN stats, LDS transpose, bf16 NCHW z writes ----
    int lane15 = lane & 15;
    float b0 = cb[(n << 5) + lane15];
    float b1 = cb[(n << 5) + 16 + lane15];
    float v00 = acc0.x + b0, v01 = acc0.y + b0, v02 = acc0.z + b0, v03 = acc0.w + b0;
    float v10 = acc1.x + b1, v11 = acc1.y + b1, v12 = acc1.z + b1, v13 = acc1.w + b1;
    float s0 = v00 + v01 + v02 + v03;
    float q0 = v00 * v00 + v01 * v01 + v02 * v02 + v03 * v03;
    float s1 = v10 + v11 + v12 + v13;
    float q1 = v10 * v10 + v11 * v11 + v12 * v12 + v13 * v13;
    if (t < 16) { redS[t] = 0.f; redQ[t] = 0.f; }
    __syncthreads();                      // all waves done with win/tup
    float* Z2 = (float*)&sm;
    int g0 = (n << 3) + (lane15 >> 2);
    atomicAdd(&redS[g0], s0);     atomicAdd(&redQ[g0], q0);
    atomicAdd(&redS[g0 + 4], s1); atomicAdd(&redQ[g0 + 4], q1);
    int pxb = (m << 4) + ((lane >> 4) << 2);
    int ocb = (n << 5) + lane15;
    Z2[(pxb + 0) * 65 + ocb] = v00;
    Z2[(pxb + 1) * 65 + ocb] = v01;
    Z2[(pxb + 2) * 65 + ocb] = v02;
    Z2[(pxb + 3) * 65 + ocb] = v03;
    Z2[(pxb + 0) * 65 + ocb + 16] = v10;
    Z2[(pxb + 1) * 65 + ocb + 16] = v11;
    Z2[(pxb + 2) * 65 + ocb + 16] = v12;
    Z2[(pxb + 3) * 65 + ocb + 16] = v13;
    __syncthreads();
    if (t < 16) {
        atomicAdd(&stats[((size_t)b * 16 + t) * 2 + 0], redS[t]);
        atomicAdd(&stats[((size_t)b * 16 + t) * 2 + 1], redQ[t]);
    }
    int oc = t >> 2, part = t & 3;
    float o0x = Z2[(part * 8 + 0) * 65 + oc];
    float o0y = Z2[(part * 8 + 1) * 65 + oc];
    float o0z = Z2[(part * 8 + 2) * 65 + oc];
    float o0w = Z2[(part * 8 + 3) * 65 + oc];
    float o1x = Z2[(part * 8 + 4) * 65 + oc];
    float o1y = Z2[(part * 8 + 5) * 65 + oc];
    float o1z = Z2[(part * 8 + 6) * 65 + oc];
    float o1w = Z2[(part * 8 + 7) * 65 + oc];
    uint4 pk;
    pk.x = pk2(o0x, o0y);
    pk.y = pk2(o0z, o0w);
    pk.z = pk2(o1x, o1y);
    pk.w = pk2(o1z, o1w);
    ushort* zp = z + (((size_t)(b << 6) + oc) << 14) + (w << 7) + (hq << 5) + part * 8;
    *(uint4*)zp = pk;
}

// ---------- GroupNorm finalize + affine + ReLU (bf16 z -> fp32 out) ----------
__global__ __launch_bounds__(256) void k_gn(const ushort* __restrict__ z,
                                            const float* __restrict__ stats,
                                            const float* __restrict__ gg,
                                            const float* __restrict__ gb,
                                            float* __restrict__ out) {
    int idx = blockIdx.x * 256 + threadIdx.x;   // grid 2048 -> 524288 threads x 8 elems
    size_t base = (size_t)idx * 8;
    int oc = (int)((base >> 14) & 63);
    int b  = (int)(base >> 20);
    int g  = oc >> 2;
    float sm = stats[((size_t)b * 16 + g) * 2 + 0];
    float sq = stats[((size_t)b * 16 + g) * 2 + 1];
    const float cnt = 65536.f;
    float mu  = sm / cnt;
    float var = sq / cnt - mu * mu;
    float inv = rsqrtf(var + EPSV);
    float gam = gg[oc] * inv;
    float bet = gb[oc] - mu * gam;
    uint4 v = *(const uint4*)(z + base);
    float4 o0, o1;
    o0.x = fmaxf(__uint_as_float(v.x << 16) * gam + bet, 0.f);
    o0.y = fmaxf(__uint_as_float(v.x & 0xffff0000u) * gam + bet, 0.f);
    o0.z = fmaxf(__uint_as_float(v.y << 16) * gam + bet, 0.f);
    o0.w = fmaxf(__uint_as_float(v.y & 0xffff0000u) * gam + bet, 0.f);
    o1.x = fmaxf(__uint_as_float(v.z << 16) * gam + bet, 0.f);
    o1.y = fmaxf(__uint_as_float(v.z & 0xffff0000u) * gam + bet, 0.f);
    o1.z = fmaxf(__uint_as_float(v.w << 16) * gam + bet, 0.f);
    o1.w = fmaxf(__uint_as_float(v.w & 0xffff0000u) * gam + bet, 0.f);
    *(float4*)(out + base) = o0;
    *(float4*)(out + base + 4) = o1;
}

extern "C" void kernel_launch(void* const* d_in, const int* in_sizes, int n_in,
                              void* d_out, int out_size, void* d_ws, size_t ws_size,
                              hipStream_t stream) {
    const float* f   = (const float*)d_in[0];
    const float* ow  = (const float*)d_in[1];
    const float* ob  = (const float*)d_in[2];
    const float* bng = (const float*)d_in[3];
    const float* bnb = (const float*)d_in[4];
    const float* bnm = (const float*)d_in[5];
    const float* bnv = (const float*)d_in[6];
    const float* cw  = (const float*)d_in[7];
    const float* cb  = (const float*)d_in[8];
    const float* gg  = (const float*)d_in[9];
    const float* gb  = (const float*)d_in[10];

    char* wsb = (char*)d_ws;
    ushort* fbh  = (ushort*)wsb;                    // 8,388,608 B (bf16 hi, NHWC)
    ushort* flo  = (ushort*)(wsb + 8388608);        // 8,388,608 B (bf16 lo residual)
    ushort* wpk  = (ushort*)(wsb + 16777216);       //    73,728 B
    ushort* wpk2 = (ushort*)(wsb + 16850944);       //    36,864 B (hi + lo frags)
    ushort* z    = (ushort*)(wsb + 16887808);       // 8,388,608 B (bf16 z)
    float*  st   = (float*)(wsb + 25276416);        //       512 B

    k_pre<<<1204, 256, 0, stream>>>(f, cw, ow, fbh, flo, wpk, wpk2, st);
    k_fused<<<2048, 256, 0, stream>>>(fbh, flo, wpk, wpk2, ob, bng, bnb, bnm, bnv, cb, z, st);
    k_gn<<<2048, 256, 0, stream>>>(z, st, gg, gb, (float*)d_out);
}

// Round 9
// 157.484 us; speedup vs baseline: 1.0342x; 1.0342x over previous
//
#include <hip/hip_runtime.h>
#include <hip/hip_bf16.h>

#define EPSV 1e-5f

typedef __attribute__((ext_vector_type(8))) short short8;
typedef __attribute__((ext_vector_type(4))) float f32x4;

__device__ __forceinline__ void gl_lds16(const void* g, void* l) {
    __builtin_amdgcn_global_load_lds(
        (const __attribute__((address_space(1))) unsigned int*)g,
        (__attribute__((address_space(3))) unsigned int*)l, 16, 0, 0);
}

__device__ __forceinline__ unsigned int bl2(unsigned int a, unsigned int b,
                                            unsigned int c, unsigned int d,
                                            float w00, float w01, float w10, float w11) {
    float lo = __uint_as_float(a << 16) * w00 + __uint_as_float(b << 16) * w01
             + __uint_as_float(c << 16) * w10 + __uint_as_float(d << 16) * w11;
    float hi = __uint_as_float(a & 0xffff0000u) * w00 + __uint_as_float(b & 0xffff0000u) * w01
             + __uint_as_float(c & 0xffff0000u) * w10 + __uint_as_float(d & 0xffff0000u) * w11;
    return ((unsigned int)__bfloat16_as_ushort(__float2bfloat16(lo)))
         | (((unsigned int)__bfloat16_as_ushort(__float2bfloat16(hi))) << 16);
}

__device__ __forceinline__ unsigned int pk2(float a, float b) {
    return ((unsigned int)__bfloat16_as_ushort(__float2bfloat16(a)))
         | (((unsigned int)__bfloat16_as_ushort(__float2bfloat16(b))) << 16);
}

// ---------- k_pre: transpose (bf16 hi+lo NHWC) + pack conv_w + pack offset_w hi/lo + zero stats ----------
__global__ __launch_bounds__(256) void k_pre(const float* __restrict__ f,
                                             const float* __restrict__ cw,
                                             const float* __restrict__ ow,
                                             ushort* __restrict__ fbh,
                                             ushort* __restrict__ flo,
                                             ushort* __restrict__ wpk,
                                             ushort* __restrict__ wpk2,
                                             float* __restrict__ stats) {
    int blk = blockIdx.x;
    int t = threadIdx.x;
    if (blk < 1024) {
        __shared__ float tile[64][65];
        int xt = blk & 1;
        int y  = (blk >> 1) & 127;
        int b  = blk >> 8;
        int x = t & 63, c0 = t >> 6;
#pragma unroll
        for (int i = 0; i < 64; i += 4)
            tile[c0 + i][x] = f[(((size_t)b * 64 + c0 + i) * 128 + y) * 128 + xt * 64 + x];
        __syncthreads();
        size_t dbase = (((size_t)b * 128 + y) * 128 + xt * 64) * 64;
        int cc = t & 63, x0 = t >> 6;
#pragma unroll
        for (int i = 0; i < 64; i += 4) {
            float v = tile[cc][x0 + i];
            ushort hi = __bfloat16_as_ushort(__float2bfloat16(v));
            float vhi = __uint_as_float((unsigned int)hi << 16);
            ushort lo = __bfloat16_as_ushort(__float2bfloat16(v - vhi));
            fbh[dbase + (size_t)(x0 + i) * 64 + cc] = hi;
            flo[dbase + (size_t)(x0 + i) * 64 + cc] = lo;
        }
    } else if (blk < 1168) {
        int idx = (blk - 1024) * 256 + t;   // 36864
        int j  = idx & 7;
        int l  = (idx >> 3) & 63;
        int ot = (idx >> 9) & 3;
        int kk = (idx >> 11) & 1;
        int k  = idx >> 12;
        int c  = kk * 32 + ((l >> 4) << 3) + j;
        int oc = (ot << 4) + (l & 15);
        wpk[idx] = __bfloat16_as_ushort(__float2bfloat16(cw[((size_t)oc * 64 + c) * 9 + k]));
        if (idx < 128) stats[idx] = 0.f;
    } else {
        int idx = (blk - 1168) * 256 + t;   // 9216
        int j   = idx & 7;
        int l   = (idx >> 3) & 63;
        int kk  = (idx >> 9) & 1;
        int tap = idx >> 10;
        int c   = kk * 32 + ((l >> 4) << 3) + j;
        int n   = l & 15;
        float v = (n < 9) ? ow[((size_t)n * 64 + c) * 9 + tap] : 0.f;
        ushort hi = __bfloat16_as_ushort(__float2bfloat16(v));
        float vhi = __uint_as_float((unsigned int)hi << 16);
        ushort lo = __bfloat16_as_ushort(__float2bfloat16(v - vhi));
        wpk2[idx] = hi;
        wpk2[idx + 9216] = lo;
    }
}

// ---------- k_fused: 7-row LDS window; offset conv (split-bf16 MFMA) + sample + main MFMA + GN stats ----------
// window rows phys {w-1,w,w+1,w-3,w-2,w+2,w+3} x 41 cols x 64ch bf16; row = 5248 B
// per (row,col): 8 chunks of 16B; chunk d holds source chunk d^(col&7)  [T21 swizzle]
__global__ __launch_bounds__(256, 4) void k_fused(
    const ushort* __restrict__ fbh,
    const ushort* __restrict__ flo,
    const ushort* __restrict__ wpk,
    const ushort* __restrict__ wpk2,
    const float* __restrict__ ob, const float* __restrict__ bng,
    const float* __restrict__ bnb, const float* __restrict__ bnm,
    const float* __restrict__ bnv, const float* __restrict__ cb,
    ushort* __restrict__ z, float* __restrict__ stats)
{
    __shared__ struct {
        ushort win[18368];          // 36736 B
        float  wy0a[288];           // 1152 B (cs overlay during phase 0)
        float  wy1a[288];           // 1152 B
        unsigned int rowsa[288];    // 1152 B
        float  redS[16];
        float  redQ[16];            // total 40320 B -> 4 blocks/CU
    } smx;

    int jb = blockIdx.x;                 // grid 2048, chunked XCD swizzle
    int orig = (jb & 7) * 256 + (jb >> 3);
    int hq = orig & 3;
    int w  = (orig >> 2) & 127;
    int b  = orig >> 9;
    int h0 = hq << 5;
    int t    = threadIdx.x;
    int lane = t & 63;
    int wid  = t >> 6;
    int m = wid & 1;
    int n = wid >> 1;
    char* winb = (char*)smx.win;

    // ---- stage window: 8 full passes + 248-thread tail; rows w-1..w+1 (phys 0-2) first ----
#pragma unroll
    for (int p = 0; p < 9; ++p) {
        if (p == 8 && t >= 248) break;       // 8*4096 + 248*16 = 36736
        int ib = p * 4096 + t * 16;
        int ri = ib / 5248;                   // phys row 0..6
        int wb = ib - ri * 5248;
        int dy = ri < 3 ? ri - 1 : (ri < 5 ? ri - 6 : ri - 3);
        int grow = min(max(w + dy, 0), 127);
        int colIdx = wb >> 7;                 // 0..40
        int c16 = (wb >> 4) & 7;
        int gcol = min(max(h0 - 5 + colIdx, 0), 127);
        int sch = c16 ^ (colIdx & 7);
        const ushort* src = fbh + ((((size_t)b << 7) + grow) * 128 + gcol) * 64 + (sch << 3);
        gl_lds16(src, (void*)(winb + ib));
    }
    asm volatile("s_waitcnt vmcnt(5)" ::: "memory");   // oldest 4 passes done -> rows w-1..w+1 ready
    __builtin_amdgcn_sched_barrier(0);
    __syncthreads();

    // ---- phase 0: offset conv, waves 0-1; hi from window, lo from global; flo pipelined; dual acc ----
    if (wid < 2) {
        f32x4 accA = {0.f, 0.f, 0.f, 0.f};
        f32x4 accB = {0.f, 0.f, 0.f, 0.f};
        const short8* wp2 = (const short8*)wpk2;
        int px0 = (m << 4) + (lane & 15);
        int q = lane >> 4;
        uint4 z4 = make_uint4(0u, 0u, 0u, 0u);
        uint4 ch0, ch1, cl0, cl1, nh0, nh1, nl0, nl1;

#define LOADT(TAP, H0, H1, L0, L1)                                              \
        {                                                                       \
            int dy_ = (TAP) / 3, dx_ = (TAP) - dy_ * 3;                         \
            int ysrc_ = w + dy_ - 1;                                            \
            int col_ = h0 + px0 + dx_ - 1;                                      \
            bool ok_ = ((unsigned)col_ < 128u) && ((unsigned)ysrc_ < 128u);     \
            int xslot_ = px0 + dx_ + 4;                                         \
            int rbase_ = dy_ * 5248 + (xslot_ << 7);                            \
            H0 = *(const uint4*)(winb + rbase_ + ((q ^ (xslot_ & 7)) << 4));    \
            H1 = *(const uint4*)(winb + rbase_ + (((q + 4) ^ (xslot_ & 7)) << 4)); \
            int colc_ = min(max(col_, 0), 127);                                 \
            int ysc_ = min(max(ysrc_, 0), 127);                                 \
            const ushort* lsrc_ = flo + ((((size_t)b << 7) + ysc_) * 128 + colc_) * 64 + (q << 3); \
            L0 = *(const uint4*)lsrc_;                                          \
            L1 = *(const uint4*)(lsrc_ + 32);                                   \
            if (!ok_) { H0 = z4; H1 = z4; L0 = z4; L1 = z4; }                   \
        }

        LOADT(0, ch0, ch1, cl0, cl1);
#pragma unroll
        for (int tap = 0; tap < 9; ++tap) {
            if (tap < 8) LOADT(tap + 1, nh0, nh1, nl0, nl1);
            short8 wh0 = wp2[(tap * 2 + 0) * 64 + lane];
            short8 wh1 = wp2[(tap * 2 + 1) * 64 + lane];
            short8 wl0 = wp2[1152 + (tap * 2 + 0) * 64 + lane];
            short8 wl1 = wp2[1152 + (tap * 2 + 1) * 64 + lane];
            short8 ah0 = *(short8*)&ch0, ah1 = *(short8*)&ch1;
            short8 al0 = *(short8*)&cl0, al1 = *(short8*)&cl1;
            accA = __builtin_amdgcn_mfma_f32_16x16x32_bf16(ah0, wh0, accA, 0, 0, 0);
            accB = __builtin_amdgcn_mfma_f32_16x16x32_bf16(ah1, wh1, accB, 0, 0, 0);
            accA = __builtin_amdgcn_mfma_f32_16x16x32_bf16(al0, wh0, accA, 0, 0, 0);
            accB = __builtin_amdgcn_mfma_f32_16x16x32_bf16(al1, wh1, accB, 0, 0, 0);
            accA = __builtin_amdgcn_mfma_f32_16x16x32_bf16(ah0, wl0, accA, 0, 0, 0);
            accB = __builtin_amdgcn_mfma_f32_16x16x32_bf16(ah1, wl1, accB, 0, 0, 0);
            ch0 = nh0; ch1 = nh1; cl0 = nl0; cl1 = nl1;
        }
#undef LOADT
        float* csm = smx.wy0a;   // cs overlay
#pragma unroll
        for (int r = 0; r < 4; ++r) {
            int pxo = (m << 4) + ((lane >> 4) << 2) + r;
            int ko = lane & 15;
            if (ko < 9) csm[pxo * 9 + ko] = accA[r] + accB[r];
        }
    }
    asm volatile("s_waitcnt vmcnt(0)" ::: "memory");   // whole window landed (own wave's loads)
    __syncthreads();                                    // all waves' staging + cs visible

    // ---- finalize: BN + tanh + cumsum + y-geometry (t<32), two steps around a barrier ----
    float wy0r[9], wy1r[9];
    unsigned int pkr[9];
    if (t < 32) {
        const float* csm = smx.wy0a;
        float tk[9];
#pragma unroll
        for (int k = 0; k < 9; ++k) {
            float zz = csm[t * 9 + k] + ob[k];
            zz = (zz - bnm[k]) * rsqrtf(bnv[k] + EPSV);
            zz = zz * bng[k] + bnb[k];
            tk[k] = tanhf(zz);
        }
        float nw_[9];
        nw_[4] = 0.f;
        nw_[5] = tk[5];
        nw_[6] = nw_[5] + tk[6];
        nw_[7] = nw_[6] + tk[7];
        nw_[8] = tk[8];
        nw_[3] = tk[3];
        nw_[2] = nw_[3] + tk[2];
        nw_[1] = nw_[2] + tk[1];
        nw_[0] = tk[0];
#pragma unroll
        for (int k = 0; k < 9; ++k) {
            float ys = (float)w + nw_[k];
            int y0 = min(max((int)floorf(ys), 0), 127);
            int y1 = min(y0 + 1, 127);
            wy0r[k] = (float)y1 - ys;
            wy1r[k] = ys - (float)y0;
            int s0 = min(max(y0 - w + 3, 0), 6);
            int s1 = min(max(y1 - w + 3, 0), 6);
            int p0 = (s0 >= 2 && s0 <= 4) ? (s0 - 2) : ((s0 < 2) ? (s0 + 3) : s0);
            int p1 = (s1 >= 2 && s1 <= 4) ? (s1 - 2) : ((s1 < 2) ? (s1 + 3) : s1);
            pkr[k] = (unsigned int)(p0 * 5248) | ((unsigned int)(p1 * 5248) << 16);
        }
    }
    __syncthreads();     // cs reads complete before tup overwrite
    if (t < 32) {
#pragma unroll
        for (int k = 0; k < 9; ++k) {
            smx.wy0a[k * 32 + t]  = wy0r[k];
            smx.wy1a[k * 32 + t]  = wy1r[k];
            smx.rowsa[k * 32 + t] = pkr[k];
        }
    }
    __syncthreads();

    // ---- phase 1: per-lane bilerp fragments from window + main MFMA (no barriers) ----
    f32x4 acc0 = {0.f, 0.f, 0.f, 0.f};
    f32x4 acc1 = {0.f, 0.f, 0.f, 0.f};
    const short8* wp8 = (const short8*)wpk;
    int px = (lane & 15) + (m << 4);
    int q  = lane >> 4;
    float fpx = (float)(h0 + px);
#pragma unroll 3
    for (int k = 0; k < 9; ++k) {
        float wy0 = smx.wy0a[k * 32 + px];
        float wy1 = smx.wy1a[k * 32 + px];
        unsigned int pkw = smx.rowsa[k * 32 + px];
        int rb0 = (int)(pkw & 0xffffu);
        int rb1 = (int)(pkw >> 16);
        float xs = fpx + (-5.0f + 1.125f * (float)k);
        int x0 = min(max((int)floorf(xs), 0), 127);
        int x1 = min(x0 + 1, 127);
        float wx0 = (float)x1 - xs;
        float wx1 = xs - (float)x0;
        float w00 = wy0 * wx0, w01 = wy0 * wx1, w10 = wy1 * wx0, w11 = wy1 * wx1;
        int cx0 = min(x0 - h0 + 5, 40);
        int cx1 = min(cx0 + 1, 40);
        int qa0 = (q ^ (cx0 & 7)) << 4;
        int qa1 = (q ^ (cx1 & 7)) << 4;
        int s00 = rb0 + (cx0 << 7) + qa0, s01 = rb0 + (cx1 << 7) + qa1;
        int s10 = rb1 + (cx0 << 7) + qa0, s11 = rb1 + (cx1 << 7) + qa1;
        uint4 a00 = *(const uint4*)(winb + s00);
        uint4 a01 = *(const uint4*)(winb + s01);
        uint4 a10 = *(const uint4*)(winb + s10);
        uint4 a11 = *(const uint4*)(winb + s11);
        uint4 b00 = *(const uint4*)(winb + (s00 ^ 64));
        uint4 b01 = *(const uint4*)(winb + (s01 ^ 64));
        uint4 b10 = *(const uint4*)(winb + (s10 ^ 64));
        uint4 b11 = *(const uint4*)(winb + (s11 ^ 64));
        uint4 f0u, f1u;
        f0u.x = bl2(a00.x, a01.x, a10.x, a11.x, w00, w01, w10, w11);
        f0u.y = bl2(a00.y, a01.y, a10.y, a11.y, w00, w01, w10, w11);
        f0u.z = bl2(a00.z, a01.z, a10.z, a11.z, w00, w01, w10, w11);
        f0u.w = bl2(a00.w, a01.w, a10.w, a11.w, w00, w01, w10, w11);
        f1u.x = bl2(b00.x, b01.x, b10.x, b11.x, w00, w01, w10, w11);
        f1u.y = bl2(b00.y, b01.y, b10.y, b11.y, w00, w01, w10, w11);
        f1u.z = bl2(b00.z, b01.z, b10.z, b11.z, w00, w01, w10, w11);
        f1u.w = bl2(b00.w, b01.w, b10.w, b11.w, w00, w01, w10, w11);
        short8 af0 = *(short8*)&f0u, af1 = *(short8*)&f1u;
        int fb0 = (k * 8 + (n << 1)) * 64 + lane;
        short8 wf00 = wp8[fb0];
        short8 wf01 = wp8[fb0 + 64];
        short8 wf10 = wp8[fb0 + 256];
        short8 wf11 = wp8[fb0 + 320];
        acc0 = __builtin_amdgcn_mfma_f32_16x16x32_bf16(af0, wf00, acc0, 0, 0, 0);
        acc0 = __builtin_amdgcn_mfma_f32_16x16x32_bf16(af1, wf10, acc0, 0, 0, 0);
        acc1 = __builtin_amdgcn_mfma_f32_16x16x32_bf16(af0, wf01, acc1, 0, 0, 0);
        acc1 = __builtin_amdgcn_mfma_f32_16x16x32_bf16(af1, wf11, acc1, 0, 0, 0);
    }

    // ---- epilogue: bias, GN stats, LDS transpose (win overlay), bf16 NCHW z writes ----
    int lane15 = lane & 15;
    float b0 = cb[(n << 5) + lane15];
    float b1 = cb[(n << 5) + 16 + lane15];
    float v00 = acc0.x + b0, v01 = acc0.y + b0, v02 = acc0.z + b0, v03 = acc0.w + b0;
    float v10 = acc1.x + b1, v11 = acc1.y + b1, v12 = acc1.z + b1, v13 = acc1.w + b1;
    float s0 = v00 + v01 + v02 + v03;
    float q0 = v00 * v00 + v01 * v01 + v02 * v02 + v03 * v03;
    float s1 = v10 + v11 + v12 + v13;
    float q1 = v10 * v10 + v11 * v11 + v12 * v12 + v13 * v13;
    if (t < 16) { smx.redS[t] = 0.f; smx.redQ[t] = 0.f; }
    __syncthreads();                      // win/tup dead for all waves
    float* Z2 = (float*)&smx;
    int g0 = (n << 3) + (lane15 >> 2);
    atomicAdd(&smx.redS[g0], s0);     atomicAdd(&smx.redQ[g0], q0);
    atomicAdd(&smx.redS[g0 + 4], s1); atomicAdd(&smx.redQ[g0 + 4], q1);
    int pxb = (m << 4) + ((lane >> 4) << 2);
    int ocb = (n << 5) + lane15;
    Z2[(pxb + 0) * 65 + ocb] = v00;
    Z2[(pxb + 1) * 65 + ocb] = v01;
    Z2[(pxb + 2) * 65 + ocb] = v02;
    Z2[(pxb + 3) * 65 + ocb] = v03;
    Z2[(pxb + 0) * 65 + ocb + 16] = v10;
    Z2[(pxb + 1) * 65 + ocb + 16] = v11;
    Z2[(pxb + 2) * 65 + ocb + 16] = v12;
    Z2[(pxb + 3) * 65 + ocb + 16] = v13;
    __syncthreads();
    if (t < 16) {
        atomicAdd(&stats[((size_t)b * 16 + t) * 2 + 0], smx.redS[t]);
        atomicAdd(&stats[((size_t)b * 16 + t) * 2 + 1], smx.redQ[t]);
    }
    int oc = t >> 2, part = t & 3;
    float o0x = Z2[(part * 8 + 0) * 65 + oc];
    float o0y = Z2[(part * 8 + 1) * 65 + oc];
    float o0z = Z2[(part * 8 + 2) * 65 + oc];
    float o0w = Z2[(part * 8 + 3) * 65 + oc];
    float o1x = Z2[(part * 8 + 4) * 65 + oc];
    float o1y = Z2[(part * 8 + 5) * 65 + oc];
    float o1z = Z2[(part * 8 + 6) * 65 + oc];
    float o1w = Z2[(part * 8 + 7) * 65 + oc];
    uint4 pk;
    pk.x = pk2(o0x, o0y);
    pk.y = pk2(o0z, o0w);
    pk.z = pk2(o1x, o1y);
    pk.w = pk2(o1z, o1w);
    ushort* zp = z + (((size_t)(b << 6) + oc) << 14) + (w << 7) + (hq << 5) + part * 8;
    *(uint4*)zp = pk;
}

// ---------- GroupNorm finalize + affine + ReLU (bf16 z -> fp32 out) ----------
__global__ __launch_bounds__(256) void k_gn(const ushort* __restrict__ z,
                                            const float* __restrict__ stats,
                                            const float* __restrict__ gg,
                                            const float* __restrict__ gb,
                                            float* __restrict__ out) {
    int idx = blockIdx.x * 256 + threadIdx.x;   // grid 2048 -> 524288 threads x 8 elems
    size_t base = (size_t)idx * 8;
    int oc = (int)((base >> 14) & 63);
    int b  = (int)(base >> 20);
    int g  = oc >> 2;
    float sm = stats[((size_t)b * 16 + g) * 2 + 0];
    float sq = stats[((size_t)b * 16 + g) * 2 + 1];
    const float cnt = 65536.f;
    float mu  = sm / cnt;
    float var = sq / cnt - mu * mu;
    float inv = rsqrtf(var + EPSV);
    float gam = gg[oc] * inv;
    float bet = gb[oc] - mu * gam;
    uint4 v = *(const uint4*)(z + base);
    float4 o0, o1;
    o0.x = fmaxf(__uint_as_float(v.x << 16) * gam + bet, 0.f);
    o0.y = fmaxf(__uint_as_float(v.x & 0xffff0000u) * gam + bet, 0.f);
    o0.z = fmaxf(__uint_as_float(v.y << 16) * gam + bet, 0.f);
    o0.w = fmaxf(__uint_as_float(v.y & 0xffff0000u) * gam + bet, 0.f);
    o1.x = fmaxf(__uint_as_float(v.z << 16) * gam + bet, 0.f);
    o1.y = fmaxf(__uint_as_float(v.z & 0xffff0000u) * gam + bet, 0.f);
    o1.z = fmaxf(__uint_as_float(v.w << 16) * gam + bet, 0.f);
    o1.w = fmaxf(__uint_as_float(v.w & 0xffff0000u) * gam + bet, 0.f);
    *(float4*)(out + base) = o0;
    *(float4*)(out + base + 4) = o1;
}

extern "C" void kernel_launch(void* const* d_in, const int* in_sizes, int n_in,
                              void* d_out, int out_size, void* d_ws, size_t ws_size,
                              hipStream_t stream) {
    const float* f   = (const float*)d_in[0];
    const float* ow  = (const float*)d_in[1];
    const float* ob  = (const float*)d_in[2];
    const float* bng = (const float*)d_in[3];
    const float* bnb = (const float*)d_in[4];
    const float* bnm = (const float*)d_in[5];
    const float* bnv = (const float*)d_in[6];
    const float* cw  = (const float*)d_in[7];
    const float* cb  = (const float*)d_in[8];
    const float* gg  = (const float*)d_in[9];
    const float* gb  = (const float*)d_in[10];

    char* wsb = (char*)d_ws;
    ushort* fbh  = (ushort*)wsb;                    // 8,388,608 B (bf16 hi, NHWC)
    ushort* flo  = (ushort*)(wsb + 8388608);        // 8,388,608 B (bf16 lo residual)
    ushort* wpk  = (ushort*)(wsb + 16777216);       //    73,728 B
    ushort* wpk2 = (ushort*)(wsb + 16850944);       //    36,864 B (hi + lo frags)
    ushort* z    = (ushort*)(wsb + 16887808);       // 8,388,608 B (bf16 z)
    float*  st   = (float*)(wsb + 25276416);        //       512 B

    k_pre<<<1204, 256, 0, stream>>>(f, cw, ow, fbh, flo, wpk, wpk2, st);
    k_fused<<<2048, 256, 0, stream>>>(fbh, flo, wpk, wpk2, ob, bng, bnb, bnm, bnv, cb, z, st);
    k_gn<<<2048, 256, 0, stream>>>(z, st, gg, gb, (float*)d_out);
}